// Round 7
// baseline (128.345 us; speedup 1.0000x reference)
//
#include <hip/hip_runtime.h>

#define HIDDEN 4096
#define RANK   256
#define G      16      // HIDDEN / RANK
#define NTH    1024    // 16 waves, 1 block per CU (LDS-forced)
#define TPB    64      // tokens per block
#define TW     4       // tokens per wave (16 waves * 4 = 64)

typedef _Float16 h2d __attribute__((ext_vector_type(2)));   // fdot2 operand type

__device__ __forceinline__ unsigned int pkf16(float a, float b) {
    auto h = __builtin_amdgcn_cvt_pkrtz(a, b);   // v_cvt_pkrtz_f16_f32
    return __builtin_bit_cast(unsigned int, h);
}
__device__ __forceinline__ float dot2(unsigned int a, unsigned int b, float c) {
    return __builtin_amdgcn_fdot2(__builtin_bit_cast(h2d, a),
                                  __builtin_bit_cast(h2d, b), c, false);
}

// Dynamic LDS:
//   [0, 131072)      : Mp  u32[128][256] — packed f16 row-pairs of M, linear
//   [131072, 147456) : ostage f32[16 waves][256]
__global__ __launch_bounds__(NTH)
void mora_v6(const float* __restrict__ x,    // [T, HIDDEN]
             const float* __restrict__ Mg,   // [RANK, RANK]
             float* __restrict__ out)        // [T, HIDDEN]
{
    extern __shared__ unsigned char smem[];
    unsigned int* Mp  = (unsigned int*)smem;
    float* ostage     = (float*)(smem + 131072);

    const int tid = threadIdx.x;
    const int w   = tid >> 6;   // wave 0..15
    const int l   = tid & 63;   // lane

    // ---- A: issue M global loads now; they land while phase 1 streams x ----
    float ma[32], mb[32];
    #pragma unroll
    for (int o = 0; o < 32; ++o) {
        const int idx = tid + (o << 10);    // u32 index in Mp [0, 32768)
        const int pr  = idx >> 8;           // pair row 0..127
        const int k   = idx & 255;          // column (lanes -> consecutive k)
        ma[o] = Mg[(size_t)(2 * pr)     * RANK + k];
        mb[o] = Mg[(size_t)(2 * pr + 1) * RANK + k];
    }

    // ---- B: phase 1 — comp entirely in registers, packed f16 pairs ----
    // lane l owns rows 4l..4l+3  ==  pairs 2l (cp0) and 2l+1 (cp1)
    const long tok0 = (long)blockIdx.x * TPB + (long)w * TW;
    unsigned int cp0[TW], cp1[TW];
    #pragma unroll
    for (int t = 0; t < TW; ++t) {
        const float4* xr = (const float4*)(x + (tok0 + t) * HIDDEN);
        float4 a = xr[l];
        #pragma unroll
        for (int gi = 1; gi < G; ++gi) {
            const float4 v = xr[l + (gi << 6)];
            a.x += v.x; a.y += v.y; a.z += v.z; a.w += v.w;
        }
        cp0[t] = pkf16(a.x, a.y);
        cp1[t] = pkf16(a.z, a.w);
    }

    // ---- C: finish M staging (contiguous ds_write_b32, conflict-free) ----
    #pragma unroll
    for (int o = 0; o < 32; ++o)
        Mp[tid + (o << 10)] = pkf16(ma[o], mb[o]);
    __syncthreads();

    // ---- D: phase 2 — acc[t][c] = sum_r comp[t][r] * M[r][4l+c] ----
    // Per iter: rows 8i..8i+7 (pairs 4i..4i+3). M reads are wave-contiguous
    // 1 KiB ds_read_b128 (no conflicts). comp pairs come via v_readlane
    // (uniform lane index) -> SGPR operand of v_dot2_f32_f16.
    float acc[TW][4];
    #pragma unroll
    for (int t = 0; t < TW; ++t) {
        acc[t][0] = 0.f; acc[t][1] = 0.f; acc[t][2] = 0.f; acc[t][3] = 0.f;
    }

    #pragma unroll 8
    for (int i = 0; i < 32; ++i) {
        const uint4 m0 = *((const uint4*)(Mp + (i * 4 + 0) * RANK) + l);
        const uint4 m1 = *((const uint4*)(Mp + (i * 4 + 1) * RANK) + l);
        const uint4 m2 = *((const uint4*)(Mp + (i * 4 + 2) * RANK) + l);
        const uint4 m3 = *((const uint4*)(Mp + (i * 4 + 3) * RANK) + l);
        #pragma unroll
        for (int t = 0; t < TW; ++t) {
            const unsigned sA = (unsigned)__builtin_amdgcn_readlane((int)cp0[t], 2 * i);
            const unsigned sB = (unsigned)__builtin_amdgcn_readlane((int)cp1[t], 2 * i);
            const unsigned sC = (unsigned)__builtin_amdgcn_readlane((int)cp0[t], 2 * i + 1);
            const unsigned sD = (unsigned)__builtin_amdgcn_readlane((int)cp1[t], 2 * i + 1);
            acc[t][0] = dot2(sA, m0.x, acc[t][0]);
            acc[t][1] = dot2(sA, m0.y, acc[t][1]);
            acc[t][2] = dot2(sA, m0.z, acc[t][2]);
            acc[t][3] = dot2(sA, m0.w, acc[t][3]);
            acc[t][0] = dot2(sB, m1.x, acc[t][0]);
            acc[t][1] = dot2(sB, m1.y, acc[t][1]);
            acc[t][2] = dot2(sB, m1.z, acc[t][2]);
            acc[t][3] = dot2(sB, m1.w, acc[t][3]);
            acc[t][0] = dot2(sC, m2.x, acc[t][0]);
            acc[t][1] = dot2(sC, m2.y, acc[t][1]);
            acc[t][2] = dot2(sC, m2.z, acc[t][2]);
            acc[t][3] = dot2(sC, m2.w, acc[t][3]);
            acc[t][0] = dot2(sD, m3.x, acc[t][0]);
            acc[t][1] = dot2(sD, m3.y, acc[t][1]);
            acc[t][2] = dot2(sD, m3.z, acc[t][2]);
            acc[t][3] = dot2(sD, m3.w, acc[t][3]);
        }
    }

    // ---- E: phase 3 — per-wave LDS restage + coalesced splat stores ----
    // lane holds cols 4l..4l+3; store instr s needs col 16s + (l>>2).
    float* ost = ostage + w * RANK;   // 1 KiB per wave
    #pragma unroll
    for (int t = 0; t < TW; ++t) {
        *(((float4*)ost) + l) =
            make_float4(acc[t][0], acc[t][1], acc[t][2], acc[t][3]);
        // same-wave LDS RAW/WAR: compiler inserts lgkmcnt waits
        float4* orow = (float4*)(out + (tok0 + t) * HIDDEN);
        #pragma unroll
        for (int s = 0; s < 16; ++s) {
            const float v = ost[(s << 4) + (l >> 2)];  // 16 banks, 4-lane bcast
            orow[(s << 6) + l] = make_float4(v, v, v, v);
        }
    }
}

extern "C" void kernel_launch(void* const* d_in, const int* in_sizes, int n_in,
                              void* d_out, int out_size, void* d_ws, size_t ws_size,
                              hipStream_t stream) {
    const float* x = (const float*)d_in[0];
    const float* M = (const float*)d_in[1];
    float* out     = (float*)d_out;

    const int T = in_sizes[0] / HIDDEN;   // 16384 tokens
    const int smem_bytes = 147456;        // 144 KiB dynamic LDS

    (void)hipFuncSetAttribute((const void*)mora_v6,
                              hipFuncAttributeMaxDynamicSharedMemorySize,
                              smem_bytes);

    hipLaunchKernelGGL(mora_v6, dim3(T / TPB), dim3(NTH), smem_bytes,
                       stream, x, M, out);
}